// Round 10
// baseline (986.479 us; speedup 1.0000x reference)
//
#include <hip/hip_runtime.h>

typedef short bf16x8 __attribute__((ext_vector_type(8)));
typedef float f32x4 __attribute__((ext_vector_type(4)));
typedef unsigned short us8 __attribute__((ext_vector_type(8)));
typedef unsigned short us2 __attribute__((ext_vector_type(2)));

__device__ __forceinline__ float bf2f(unsigned short u) {
    union { unsigned i; float f; } v; v.i = ((unsigned)u) << 16; return v.f;
}
__device__ __forceinline__ unsigned short f2bf(float f) {
    union { float f; unsigned i; } v; v.f = f;
    unsigned r = v.i + 0x7fffu + ((v.i >> 16) & 1u);   // RNE
    return (unsigned short)(r >> 16);
}
__device__ __forceinline__ float ldflex(const void* p, int isf32, long i) {
    return isf32 ? ((const float*)p)[i] : bf2f(((const unsigned short*)p)[i]);
}
// Fast exact-gelu: A&S 7.1.26 minimax erf, |err| <= 1.5e-7 (<< bf16 quantum).
__device__ __forceinline__ float gelu_exact(float v) {
    const float x = fabsf(v) * 0.70710678118654752f;
    const float t = __builtin_amdgcn_rcpf(fmaf(0.3275911f, x, 1.0f));
    float p = fmaf(1.061405429f, t, -1.453152027f);
    p = fmaf(p, t, 1.421413741f);
    p = fmaf(p, t, -0.284496736f);
    p = fmaf(p, t, 0.254829592f);
    p *= t;
    const float e = __expf(-x * x);
    const float erfv = copysignf(fmaf(-p, e, 1.0f), v);
    return 0.5f * v * (1.0f + erfv);
}
__device__ __forceinline__ us8 pack8u(const float* s) {
    us8 r;
    #pragma unroll
    for (int i = 0; i < 8; ++i) r[i] = f2bf(s[i]);
    return r;
}
// HW paired f32->bf16 (RNE), 1 instr for 2 values.
__device__ __forceinline__ unsigned cvtpk_bf16(float lo, float hi) {
    unsigned u;
    asm("v_cvt_pk_bf16_f32 %0, %1, %2" : "=v"(u) : "v"(lo), "v"(hi));
    return u;
}

// Async global->LDS, 16B per lane. LDS dest must be wave-uniform base + lane*16.
__device__ __forceinline__ void gld16(const void* g, void* l) {
    typedef __attribute__((address_space(1))) void GV;
    typedef __attribute__((address_space(3))) void LV;
    __builtin_amdgcn_global_load_lds((GV*)g, (LV*)l, 16, 0, 0);
}

// ---------------------------------------------------------------------------
// Fused dtype sniffer: block i classifies tensor i. 1=fp32, 0=bf16.
// ---------------------------------------------------------------------------
struct SniffArgs { const void* p[13]; int n[13]; };

__global__ __launch_bounds__(64) void sniff_all(SniffArgs a, int* __restrict__ flags)
{
    const unsigned short* buf = (const unsigned short*)a.p[blockIdx.x];
    const int n_elems = a.n[blockIdx.x];
    __shared__ int cnt[3];
    if (threadIdx.x < 3) cnt[threadIdx.x] = 0;
    __syncthreads();
    int K = n_elems / 2; if (K > 1024) K = 1024; if (K < 1) K = 1;
    int ins = 0, ne = 0, no = 0;
    for (int i = threadIdx.x; i < K; i += 64) {
        const unsigned lo = buf[2 * i], hi = buf[2 * i + 1];
        const unsigned e = (lo >> 7) & 0xFF;
        ins += (lo != 0 && (e < 90 || e > 160)) ? 1 : 0;
        ne  += (lo != 0);
        no  += (hi != 0);
    }
    atomicAdd(&cnt[0], ins); atomicAdd(&cnt[1], ne); atomicAdd(&cnt[2], no);
    __syncthreads();
    if (threadIdx.x == 0)
        flags[blockIdx.x] = (cnt[0] * 10 > K) || (cnt[1] * 10 < K && cnt[2] * 2 > K);
}

// ---------------------------------------------------------------------------
// One-shot param conversion: weights (flex) -> bf16 workspace, biases -> fp32.
// ---------------------------------------------------------------------------
struct CvtArgs { const void* src[7]; void* dst[7]; int fidx[7]; int n[7]; int tobf[7]; };

__global__ __launch_bounds__(256) void convert_params(CvtArgs a, const int* __restrict__ flags)
{
    const int t = blockIdx.y;
    const int i0 = (blockIdx.x * 256 + threadIdx.x) * 8;
    if (i0 >= a.n[t]) return;
    const int f = flags[a.fidx[t]];
    float v[8];
    if (f) {
        const float* s = (const float*)a.src[t] + i0;
        *(f32x4*)&v[0] = *(const f32x4*)s;
        *(f32x4*)&v[4] = *(const f32x4*)(s + 4);
    } else {
        us8 u = *(const us8*)((const unsigned short*)a.src[t] + i0);
        #pragma unroll
        for (int i = 0; i < 8; ++i) v[i] = bf2f(u[i]);
    }
    if (a.tobf[t]) {
        *(us8*)((unsigned short*)a.dst[t] + i0) = pack8u(v);
    } else {
        float* d = (float*)a.dst[t] + i0;
        *(f32x4*)d       = *(f32x4*)&v[0];
        *(f32x4*)(d + 4) = *(f32x4*)&v[4];
    }
}

// ---------------------------------------------------------------------------
// Pure-bf16 MFMA GEMM with 2-deep counted-vmcnt pipeline; LDS slot-XOR
// swizzle; 128x128 tile, BK=32, 4 waves. XCD-bijective swizzle.
// (round-4/7 proven config — frozen this round)
// ---------------------------------------------------------------------------
__global__ __launch_bounds__(256) void gemm_bf16(
    const unsigned short* __restrict__ A, const unsigned short* __restrict__ W,
    void* __restrict__ C, int Nout, int K,
    const float* __restrict__ bias,
    const void* resid, const int* rflag, long resid_row0,
    int act, int out_bf16)
{
    __shared__ unsigned short As[2][128 * 32];
    __shared__ unsigned short Bs[2][128 * 32];
    const int tid  = threadIdx.x;
    const int lane = tid & 63, wv = tid >> 6;
    const int wrow = wv >> 1, wcol = wv & 1;
    const int fm = lane & 15, quad = lane >> 4;

    const int gx = gridDim.x;
    const int nwg = gx * gridDim.y;
    int lin = blockIdx.y * gx + blockIdx.x;
    lin = (lin & 7) * (nwg >> 3) + (lin >> 3);
    const int bm = (lin / gx) * 128, bn = (lin % gx) * 128;

    const int sr   = tid >> 2;
    const int sb   = (((tid & 3) ^ ((sr >> 1) & 3)) * 16);
    const char* Ab = (const char*)A;
    const char* Wb = (const char*)W;
    const long a0 = ((long)(bm + sr) * K) * 2 + sb;
    const long a1 = ((long)(bm + 64 + sr) * K) * 2 + sb;
    const long b0 = ((long)(bn + sr) * K) * 2 + sb;
    const long b1 = ((long)(bn + 64 + sr) * K) * 2 + sb;
    const int ld = tid * 16;

    auto stage = [&](int bsel, int k0b) {
        char* AD = (char*)As[bsel];
        char* BD = (char*)Bs[bsel];
        gld16(Ab + a0 + k0b, AD + ld);
        gld16(Ab + a1 + k0b, AD + 4096 + ld);
        gld16(Wb + b0 + k0b, BD + ld);
        gld16(Wb + b1 + k0b, BD + 4096 + ld);
    };

    f32x4 acc[4][4] = {};
    const int nt = (K * 2) / 64;

    const int xsw = (fm >> 1) & 3;

    stage(0, 0);
    stage(1, 64);
    int cur = 0;
    for (int t = 0; t < nt; ++t) {
        if (t + 1 < nt) { asm volatile("s_waitcnt vmcnt(4)" ::: "memory"); }
        else            { asm volatile("s_waitcnt vmcnt(0)" ::: "memory"); }
        __builtin_amdgcn_sched_barrier(0);
        __builtin_amdgcn_s_barrier();
        __builtin_amdgcn_sched_barrier(0);

        const unsigned short* Ac = As[cur];
        const unsigned short* Bc = Bs[cur];
        bf16x8 af[4], bw[4];
        #pragma unroll
        for (int u = 0; u < 4; ++u) {
            const int qs = (quad ^ xsw) * 8;
            af[u] = *(const bf16x8*)&Ac[(wrow * 64 + u * 16 + fm) * 32 + qs];
            bw[u] = *(const bf16x8*)&Bc[(wcol * 64 + u * 16 + fm) * 32 + qs];
        }
        __builtin_amdgcn_s_setprio(1);
        #pragma unroll
        for (int i = 0; i < 4; ++i)
            #pragma unroll
            for (int j = 0; j < 4; ++j)
                acc[i][j] = __builtin_amdgcn_mfma_f32_16x16x32_bf16(
                                af[i], bw[j], acc[i][j], 0, 0, 0);
        __builtin_amdgcn_s_setprio(0);

        asm volatile("s_waitcnt lgkmcnt(0)" ::: "memory");
        __builtin_amdgcn_sched_barrier(0);
        __builtin_amdgcn_s_barrier();
        __builtin_amdgcn_sched_barrier(0);
        if (t + 2 < nt) stage(cur, (t + 2) * 64);
        cur ^= 1;
    }

    const int crow0 = bm + wrow * 64, ccol0 = bn + wcol * 64;
    if (out_bf16) {
        unsigned short* Cb = (unsigned short*)C;
        #pragma unroll
        for (int j = 0; j < 4; ++j) {
            const int col = ccol0 + j * 16 + fm;
            const float bv = bias ? bias[col] : 0.0f;
            #pragma unroll
            for (int i = 0; i < 4; ++i)
                #pragma unroll
                for (int r = 0; r < 4; ++r) {
                    const int row = crow0 + i * 16 + quad * 4 + r;
                    float v = acc[i][j][r] + bv;
                    if (act) v = gelu_exact(v);
                    Cb[(long)row * Nout + col] = f2bf(v);
                }
        }
    } else {
        float* Cf = (float*)C;
        const int rfl = resid ? (rflag ? *rflag : 1) : 1;
        #pragma unroll
        for (int j = 0; j < 4; ++j) {
            const int col = ccol0 + j * 16 + fm;
            const float bv = bias ? bias[col] : 0.0f;
            #pragma unroll
            for (int i = 0; i < 4; ++i)
                #pragma unroll
                for (int r = 0; r < 4; ++r) {
                    const int row = crow0 + i * 16 + quad * 4 + r;
                    float v = acc[i][j][r] + bv;
                    if (act)   v = gelu_exact(v);
                    if (resid) v += ldflex(resid, rfl, (resid_row0 + row) * (long)Nout + col);
                    Cf[(long)row * Nout + col] = v;
                }
        }
    }
}

// ---------------------------------------------------------------------------
// LayerNorm over rows of 512. Flex-dtype x/g/b; bf16 out. Vectorized loads:
// fp32 path = float2 (8B/lane coalesced), bf16 path = packed uint.
// ---------------------------------------------------------------------------
__global__ __launch_bounds__(256) void layernorm_512(
    const void* __restrict__ x, const int* __restrict__ xflag, long row0,
    const void* __restrict__ g, const int* __restrict__ gflag,
    const void* __restrict__ b, const int* __restrict__ bflag,
    unsigned short* __restrict__ o)
{
    const int row = blockIdx.x;
    const int tid = threadIdx.x;
    const int xf = xflag ? *xflag : 1;
    float vx, vy;
    if (xf) {
        const float2 t = ((const float2*)x)[(row0 + row) * 256 + tid];
        vx = t.x; vy = t.y;
    } else {
        const unsigned u = ((const unsigned*)x)[(row0 + row) * 256 + tid];
        vx = bf2f((unsigned short)u); vy = bf2f((unsigned short)(u >> 16));
    }
    float s  = vx + vy;
    float s2 = vx * vx + vy * vy;
    #pragma unroll
    for (int off = 32; off > 0; off >>= 1) {
        s  += __shfl_down(s, off);
        s2 += __shfl_down(s2, off);
    }
    __shared__ float ss[4], ss2[4];
    if ((tid & 63) == 0) { ss[tid >> 6] = s; ss2[tid >> 6] = s2; }
    __syncthreads();
    const float ts   = ss[0] + ss[1] + ss[2] + ss[3];
    const float ts2  = ss2[0] + ss2[1] + ss2[2] + ss2[3];
    const float mean = ts * (1.0f / 512.0f);
    const float var  = ts2 * (1.0f / 512.0f) - mean * mean;
    const float rstd = rsqrtf(var + 1e-5f);
    const int gf = *gflag, bff = *bflag;
    float gx_, gy_, bx_, by_;
    if (gf) { const float2 t = ((const float2*)g)[tid]; gx_ = t.x; gy_ = t.y; }
    else    { const unsigned u = ((const unsigned*)g)[tid];
              gx_ = bf2f((unsigned short)u); gy_ = bf2f((unsigned short)(u >> 16)); }
    if (bff) { const float2 t = ((const float2*)b)[tid]; bx_ = t.x; by_ = t.y; }
    else     { const unsigned u = ((const unsigned*)b)[tid];
               bx_ = bf2f((unsigned short)u); by_ = bf2f((unsigned short)(u >> 16)); }
    us2 r;
    r[0] = f2bf((vx - mean) * rstd * gx_ + bx_);
    r[1] = f2bf((vy - mean) * rstd * gy_ + by_);
    *(us2*)(o + (long)row * 512 + tid * 2) = r;
}

// ---------------------------------------------------------------------------
// MFMA flash attention, bf16 qkv in [b,n,3,H,64], bf16 o out [b,n,H,64].
// K/V register-prefetched one tile ahead; raw-barrier phase 2. Row-sum via
// ones-column MFMA. Defer-max (T13, THR=8): skip acc/accS rescale + mrow
// update when tile max grew <= 8 (wave-uniform; P bounded by e^8).
// ---------------------------------------------------------------------------
__global__ __launch_bounds__(256, 5) void attn_mfma(
    const unsigned short* __restrict__ qkv,
    const void* __restrict__ table, const int* __restrict__ tflag,
    unsigned short* __restrict__ o)
{
    __shared__ unsigned short Ks[512 * 8];     // fragment-linear K, 8 KB
    __shared__ unsigned short Vt[64 * 72];     // [d][key]   9.2 KB
    __shared__ unsigned short Pl[4][16 * 72];  // per-wave P [q][key] 9.2 KB
    __shared__ float Tbh[228];                 // padded per-head bias column

    const int tid  = threadIdx.x;
    const int lane = tid & 63, wv = tid >> 6;
    const int fm = lane & 15, quad = lane >> 4;

    // XCD-bijective swizzle: total = 128*nb, always divisible by 8.
    const int hw    = blockIdx.x + gridDim.x * (blockIdx.y + gridDim.y * blockIdx.z);
    const int total = gridDim.x * gridDim.y * gridDim.z;
    const int lin   = (hw & 7) * (total >> 3) + (hw >> 3);
    const int q0 = (lin & 15) * 64;
    const int h  = (lin >> 4) & 7;
    const int b  = lin >> 7;

    {   // cache this head's bias column, padded [225..227] = [224]
        const int tf = *tflag;
        if (tid < 228) {
            const int src = tid > 224 ? 224 : tid;
            Tbh[tid] = ldflex(table, tf, src * 8 + h);
        }
    }

    // Q fragments: A[m=fm -> q][k=quad*8+j -> d], 2 chains (d 0..31, 32..63)
    bf16x8 qa[2];
    {
        const unsigned short* qb = &qkv[(long)((b * 1024 + q0 + wv * 16 + fm) * 3) * 512
                                        + h * 64 + quad * 8];
        qa[0] = *(const bf16x8*)qb;
        qa[1] = *(const bf16x8*)(qb + 32);
    }

    // rel-pos bias running indices: idx_raw[c] decremented 126/tile; >=0 always
    const int qi0   = q0 + wv * 16 + quad * 4;
    const int base0 = 63 * (qi0 >> 5) + (qi0 & 31) + 1984;
    int idxr[4];
    #pragma unroll
    for (int c = 0; c < 4; ++c) {
        const int kj = c * 16 + fm;
        idxr[c] = base0 - (63 * (kj >> 5) + (kj & 31));
    }

    // ones B-frag for row-sum MFMA
    bf16x8 ones8;
    #pragma unroll
    for (int i = 0; i < 8; ++i) ones8[i] = (short)0x3F80;

    // K staging chunk decode (fragment-linear; 2 b128 writes per thread)
    const int kc_fm   = tid & 15;
    const int kc_quad = (tid >> 4) & 3;
    const int kc_ch   = (tid >> 6) & 1;
    const int kc_c0   = (tid >> 7) & 1;
    const char* qkvB  = (const char*)qkv;
    long ksrc = (((long)(b * 1024 + kc_c0 * 16 + kc_fm) * 3 + 1) * 512
                 + h * 64 + kc_ch * 32 + kc_quad * 8) * 2;

    // V staging: key = lane (conflict-free transpose writes), d-chunk = wave
    const int key_v = tid & 63;
    const int dv    = (tid >> 6) * 16;
    long vsrc = (((long)(b * 1024 + key_v) * 3 + 2) * 512 + h * 64 + dv) * 2;

    char* KsB = (char*)Ks;

    f32x4 acc[4] = {};          // O accumulator: col-tile c -> d, rows quad*4+r
    f32x4 accS = {};            // row-sum accumulator (online l)
    float mrow[4] = {-1e30f, -1e30f, -1e30f, -1e30f};

    // prologue: prefetch tile 0 K/V into registers
    us8 kv0 = *(const us8*)(qkvB + ksrc);
    us8 kv1 = *(const us8*)(qkvB + ksrc + 98304);
    us8 vv0 = *(const us8*)(qkvB + vsrc);
    us8 vv1 = *(const us8*)(qkvB + vsrc + 16);

    for (int kt = 0; kt < 16; ++kt) {
        __syncthreads();   // prior tile's LDS reads done (and Tbh/qa on iter 0)

        // write prefetched K/V regs to LDS
        *(us8*)(KsB + tid * 16)        = kv0;
        *(us8*)(KsB + 4096 + tid * 16) = kv1;
        #pragma unroll
        for (int i = 0; i < 8; ++i) Vt[(dv + i) * 72 + key_v]     = vv0[i];
        #pragma unroll
        for (int i = 0; i < 8; ++i) Vt[(dv + 8 + i) * 72 + key_v] = vv1[i];

        // issue NEXT tile's loads (stay in flight through this tile's compute)
        if (kt < 15) {
            ksrc += 196608; vsrc += 196608;
            kv0 = *(const us8*)(qkvB + ksrc);
            kv1 = *(const us8*)(qkvB + ksrc + 98304);
            vv0 = *(const us8*)(qkvB + vsrc);
            vv1 = *(const us8*)(qkvB + vsrc + 16);
        }

        // barrier2: LDS writes visible; does NOT drain vmcnt (prefetch lives)
        asm volatile("s_waitcnt lgkmcnt(0)" ::: "memory");
        __builtin_amdgcn_s_barrier();

        // S = Q K^T  (4 col-tiles x 2 k-chains), Ks reads = base + lane*16
        f32x4 sv[4];
        __builtin_amdgcn_s_setprio(1);
        #pragma unroll
        for (int c = 0; c < 4; ++c) {
            f32x4 z = {};
            z = __builtin_amdgcn_mfma_f32_16x16x32_bf16(
                    qa[0], *(const bf16x8*)&Ks[(((c * 2 + 0) * 4 + quad) * 16 + fm) * 8],
                    z, 0, 0, 0);
            z = __builtin_amdgcn_mfma_f32_16x16x32_bf16(
                    qa[1], *(const bf16x8*)&Ks[(((c * 2 + 1) * 4 + quad) * 16 + fm) * 8],
                    z, 0, 0, 0);
            sv[c] = z;
        }
        __builtin_amdgcn_s_setprio(0);

        // scale + rel-pos bias: idx_r = idx_0 + r into padded table
        #pragma unroll
        for (int c = 0; c < 4; ++c) {
            const int i0 = idxr[c] > 224 ? 224 : idxr[c];
            const float* tb = &Tbh[i0];
            idxr[c] -= 126;
            #pragma unroll
            for (int r = 0; r < 4; ++r)
                sv[c][r] = fmaf(sv[c][r], 0.125f, tb[r]);
        }

        // tile max per q-row (16-lane groups: lanes share quad)
        float mr4[4];
        int defer = 1;
        #pragma unroll
        for (int r = 0; r < 4; ++r) {
            float mr = fmaxf(fmaxf(sv[0][r], sv[1][r]), fmaxf(sv[2][r], sv[3][r]));
            #pragma unroll
            for (int off = 1; off < 16; off <<= 1) mr = fmaxf(mr, __shfl_xor(mr, off));
            mr4[r] = mr;
            defer &= (mr <= mrow[r] + 8.0f) ? 1 : 0;
        }

        const bool skip_rescale = (__all(defer) != 0);
        float alpha[4];
        if (skip_rescale) {
            // T13 defer-max: keep old frame; P = exp(S - m_old) <= e^8
            #pragma unroll
            for (int r = 0; r < 4; ++r)
                #pragma unroll
                for (int c = 0; c < 4; ++c)
                    sv[c][r] = __expf(sv[c][r] - mrow[r]);
        } else {
            #pragma unroll
            for (int r = 0; r < 4; ++r) {
                const float mnew = fmaxf(mrow[r], mr4[r]);
                alpha[r] = __expf(mrow[r] - mnew);
                mrow[r] = mnew;
                #pragma unroll
                for (int c = 0; c < 4; ++c)
                    sv[c][r] = __expf(sv[c][r] - mnew);
            }
        }

        // P: C layout -> LDS [q][key] via paired cvt_pk (per-wave region)
        unsigned short* Pw = Pl[wv];
        #pragma unroll
        for (int r = 0; r < 4; ++r) {
            const unsigned u01 = cvtpk_bf16(sv[0][r], sv[1][r]);
            const unsigned u23 = cvtpk_bf16(sv[2][r], sv[3][r]);
            const int row = (quad * 4 + r) * 72;
            Pw[row + fm]      = (unsigned short)u01;
            Pw[row + 16 + fm] = (unsigned short)(u01 >> 16);
            Pw[row + 32 + fm] = (unsigned short)u23;
            Pw[row + 48 + fm] = (unsigned short)(u23 >> 16);
        }

        // PV: A frag = P[q=fm][key=chain*32+quad*8+j]; B frag = Vt[d][key]
        const bf16x8 ap0 = *(const bf16x8*)&Pw[fm * 72 + quad * 8];
        const bf16x8 ap1 = *(const bf16x8*)&Pw[fm * 72 + 32 + quad * 8];
        __builtin_amdgcn_s_setprio(1);
        if (!skip_rescale) {
            #pragma unroll
            for (int c = 0; c < 4; ++c)
                #pragma unroll
                for (int r = 0; r < 4; ++r) acc[c][r] *= alpha[r];
            #pragma unroll
            for (int r = 0; r < 4; ++r) accS[r] *= alpha[r];
        }
        #pragma unroll
        for (int c = 0; c < 4; ++c) {
            acc[c] = __builtin_amdgcn_mfma_f32_16x16x32_bf16(
                        ap0, *(const bf16x8*)&Vt[(c * 16 + fm) * 72 + quad * 8], acc[c], 0, 0, 0);
            acc[c] = __builtin_amdgcn_mfma_f32_16x16x32_bf16(
                        ap1, *(const bf16x8*)&Vt[(c * 16 + fm) * 72 + 32 + quad * 8], acc[c], 0, 0, 0);
        }
        accS = __builtin_amdgcn_mfma_f32_16x16x32_bf16(ap0, ones8, accS, 0, 0, 0);
        accS = __builtin_amdgcn_mfma_f32_16x16x32_bf16(ap1, ones8, accS, 0, 0, 0);
        __builtin_amdgcn_s_setprio(0);
    }

    float rinv[4];
    #pragma unroll
    for (int r = 0; r < 4; ++r) rinv[r] = 1.0f / accS[r];
    #pragma unroll
    for (int r = 0; r < 4; ++r) {
        const long ob = (long)(b * 1024 + q0 + wv * 16 + quad * 4 + r) * 512 + h * 64;
        const unsigned u01 = cvtpk_bf16(acc[0][r] * rinv[r], acc[1][r] * rinv[r]);
        const unsigned u23 = cvtpk_bf16(acc[2][r] * rinv[r], acc[3][r] * rinv[r]);
        o[ob + fm]      = (unsigned short)u01;
        o[ob + 16 + fm] = (unsigned short)(u01 >> 16);
        o[ob + 32 + fm] = (unsigned short)u23;
        o[ob + 48 + fm] = (unsigned short)(u23 >> 16);
    }
}

extern "C" void kernel_launch(void* const* d_in, const int* in_sizes, int n_in,
                              void* d_out, int out_size, void* d_ws, size_t ws_size,
                              hipStream_t stream)
{
    (void)n_in; (void)out_size;
    float* out = (float*)d_out;

    constexpr int B = 32, N = 1024;

    int* flags = (int*)d_ws;
    {
        SniffArgs sa;
        for (int t = 0; t < 13; ++t) { sa.p[t] = d_in[t]; sa.n[t] = in_sizes[t]; }
        sniff_all<<<13, 64, 0, stream>>>(sa, flags);
    }

    // workspace layout: flags(256) | bf16 weights | fp32 biases | bf16 scratch
    unsigned short* Wq = (unsigned short*)((char*)d_ws + 256);  // [1536,512]
    unsigned short* Wp = Wq + 786432;                           // [512,512]
    unsigned short* W1 = Wp + 262144;                           // [2048,512]
    unsigned short* W2 = W1 + 1048576;                          // [512,2048]
    float* Bp = (float*)(W2 + 1048576);                         // 512
    float* B1 = Bp + 512;                                       // 2048
    float* B2 = B1 + 2048;                                      // 512
    char* scr = (char*)(B2 + 512);
    scr = (char*)(((size_t)scr + 255) & ~(size_t)255);

    {
        CvtArgs ca;
        ca.src[0] = d_in[1]; ca.dst[0] = Wq; ca.fidx[0] = 1; ca.n[0] = 786432;  ca.tobf[0] = 1;
        ca.src[1] = d_in[2]; ca.dst[1] = Wp; ca.fidx[1] = 2; ca.n[1] = 262144;  ca.tobf[1] = 1;
        ca.src[2] = d_in[4]; ca.dst[2] = W1; ca.fidx[2] = 4; ca.n[2] = 1048576; ca.tobf[2] = 1;
        ca.src[3] = d_in[6]; ca.dst[3] = W2; ca.fidx[3] = 6; ca.n[3] = 1048576; ca.tobf[3] = 1;
        ca.src[4] = d_in[3]; ca.dst[4] = Bp; ca.fidx[4] = 3; ca.n[4] = 512;     ca.tobf[4] = 0;
        ca.src[5] = d_in[5]; ca.dst[5] = B1; ca.fidx[5] = 5; ca.n[5] = 2048;    ca.tobf[5] = 0;
        ca.src[6] = d_in[7]; ca.dst[6] = B2; ca.fidx[6] = 7; ca.n[6] = 512;     ca.tobf[6] = 0;
        convert_params<<<dim3(512, 7), 256, 0, stream>>>(ca, flags);
    }

    const size_t fixed = (size_t)(scr - (char*)d_ws);
    const size_t per_batch = (size_t)N * 3072 * 2;   // Ln(512)+Hd(2048)+Ao(512) bf16
    int bpc = (int)((ws_size - fixed) / per_batch);
    if (bpc < 1) bpc = 1;
    if (bpc > B) bpc = B;

    unsigned short* Ln = (unsigned short*)scr;
    unsigned short* Hd = Ln + (size_t)bpc * N * 512;
    unsigned short* Ao = Hd + (size_t)bpc * N * 2048;

    // Phase 1: LN1 -> qkv -> attention -> proj (+bias, +x residual)
    for (int b0 = 0; b0 < B; b0 += bpc) {
        const int nb   = (B - b0) < bpc ? (B - b0) : bpc;
        const int rows = nb * N;
        const long r0  = (long)b0 * N;

        layernorm_512<<<rows, 256, 0, stream>>>(
            d_in[0], flags + 0, r0, d_in[8], flags + 8, d_in[9], flags + 9, Ln);
        gemm_bf16<<<dim3(12, rows / 128), 256, 0, stream>>>(
            Ln, Wq, Hd, 1536, 512, nullptr, nullptr, nullptr, 0, 0, 1);
        attn_mfma<<<dim3(16, 8, nb), 256, 0, stream>>>(
            Hd, d_in[12], flags + 12, Ao);
        gemm_bf16<<<dim3(4, rows / 128), 256, 0, stream>>>(
            Ao, Wp, out + r0 * 512, 512, 512,
            Bp, d_in[0], flags + 0, r0, 0, 0);
    }

    // Phase 2: LN2 -> mlp1 (+bias, gelu) -> mlp2 (+bias, +residual in-place)
    for (int b0 = 0; b0 < B; b0 += bpc) {
        const int nb   = (B - b0) < bpc ? (B - b0) : bpc;
        const int rows = nb * N;
        const long r0  = (long)b0 * N;

        layernorm_512<<<rows, 256, 0, stream>>>(
            out + r0 * 512, nullptr, 0, d_in[10], flags + 10, d_in[11], flags + 11, Ln);
        gemm_bf16<<<dim3(16, rows / 128), 256, 0, stream>>>(
            Ln, W1, Hd, 2048, 512, B1, nullptr, nullptr, 0, 1, 1);
        gemm_bf16<<<dim3(4, rows / 128), 256, 0, stream>>>(
            Hd, W2, out + r0 * 512, 512, 2048,
            B2, out + r0 * 512, nullptr, 0, 0, 0);
    }
}

// Round 11
// 830.517 us; speedup vs baseline: 1.1878x; 1.1878x over previous
//
#include <hip/hip_runtime.h>

typedef short bf16x8 __attribute__((ext_vector_type(8)));
typedef float f32x4 __attribute__((ext_vector_type(4)));
typedef unsigned short us8 __attribute__((ext_vector_type(8)));
typedef unsigned short us2 __attribute__((ext_vector_type(2)));

__device__ __forceinline__ float bf2f(unsigned short u) {
    union { unsigned i; float f; } v; v.i = ((unsigned)u) << 16; return v.f;
}
__device__ __forceinline__ unsigned short f2bf(float f) {
    union { float f; unsigned i; } v; v.f = f;
    unsigned r = v.i + 0x7fffu + ((v.i >> 16) & 1u);   // RNE
    return (unsigned short)(r >> 16);
}
__device__ __forceinline__ float ldflex(const void* p, int isf32, long i) {
    return isf32 ? ((const float*)p)[i] : bf2f(((const unsigned short*)p)[i]);
}
// Fast exact-gelu: A&S 7.1.26 minimax erf, |err| <= 1.5e-7 (<< bf16 quantum).
__device__ __forceinline__ float gelu_exact(float v) {
    const float x = fabsf(v) * 0.70710678118654752f;
    const float t = __builtin_amdgcn_rcpf(fmaf(0.3275911f, x, 1.0f));
    float p = fmaf(1.061405429f, t, -1.453152027f);
    p = fmaf(p, t, 1.421413741f);
    p = fmaf(p, t, -0.284496736f);
    p = fmaf(p, t, 0.254829592f);
    p *= t;
    const float e = __expf(-x * x);
    const float erfv = copysignf(fmaf(-p, e, 1.0f), v);
    return 0.5f * v * (1.0f + erfv);
}
__device__ __forceinline__ us8 pack8u(const float* s) {
    us8 r;
    #pragma unroll
    for (int i = 0; i < 8; ++i) r[i] = f2bf(s[i]);
    return r;
}
// HW paired f32->bf16 (RNE), 1 instr for 2 values.
__device__ __forceinline__ unsigned cvtpk_bf16(float lo, float hi) {
    unsigned u;
    asm("v_cvt_pk_bf16_f32 %0, %1, %2" : "=v"(u) : "v"(lo), "v"(hi));
    return u;
}

// Async global->LDS, 16B per lane. LDS dest must be wave-uniform base + lane*16.
__device__ __forceinline__ void gld16(const void* g, void* l) {
    typedef __attribute__((address_space(1))) void GV;
    typedef __attribute__((address_space(3))) void LV;
    __builtin_amdgcn_global_load_lds((GV*)g, (LV*)l, 16, 0, 0);
}

// ---------------------------------------------------------------------------
// Fused dtype sniffer: block i classifies tensor i. 1=fp32, 0=bf16.
// ---------------------------------------------------------------------------
struct SniffArgs { const void* p[13]; int n[13]; };

__global__ __launch_bounds__(64) void sniff_all(SniffArgs a, int* __restrict__ flags)
{
    const unsigned short* buf = (const unsigned short*)a.p[blockIdx.x];
    const int n_elems = a.n[blockIdx.x];
    __shared__ int cnt[3];
    if (threadIdx.x < 3) cnt[threadIdx.x] = 0;
    __syncthreads();
    int K = n_elems / 2; if (K > 1024) K = 1024; if (K < 1) K = 1;
    int ins = 0, ne = 0, no = 0;
    for (int i = threadIdx.x; i < K; i += 64) {
        const unsigned lo = buf[2 * i], hi = buf[2 * i + 1];
        const unsigned e = (lo >> 7) & 0xFF;
        ins += (lo != 0 && (e < 90 || e > 160)) ? 1 : 0;
        ne  += (lo != 0);
        no  += (hi != 0);
    }
    atomicAdd(&cnt[0], ins); atomicAdd(&cnt[1], ne); atomicAdd(&cnt[2], no);
    __syncthreads();
    if (threadIdx.x == 0)
        flags[blockIdx.x] = (cnt[0] * 10 > K) || (cnt[1] * 10 < K && cnt[2] * 2 > K);
}

// ---------------------------------------------------------------------------
// One-shot param conversion: weights (flex) -> bf16 workspace, biases -> fp32.
// ---------------------------------------------------------------------------
struct CvtArgs { const void* src[7]; void* dst[7]; int fidx[7]; int n[7]; int tobf[7]; };

__global__ __launch_bounds__(256) void convert_params(CvtArgs a, const int* __restrict__ flags)
{
    const int t = blockIdx.y;
    const int i0 = (blockIdx.x * 256 + threadIdx.x) * 8;
    if (i0 >= a.n[t]) return;
    const int f = flags[a.fidx[t]];
    float v[8];
    if (f) {
        const float* s = (const float*)a.src[t] + i0;
        *(f32x4*)&v[0] = *(const f32x4*)s;
        *(f32x4*)&v[4] = *(const f32x4*)(s + 4);
    } else {
        us8 u = *(const us8*)((const unsigned short*)a.src[t] + i0);
        #pragma unroll
        for (int i = 0; i < 8; ++i) v[i] = bf2f(u[i]);
    }
    if (a.tobf[t]) {
        *(us8*)((unsigned short*)a.dst[t] + i0) = pack8u(v);
    } else {
        float* d = (float*)a.dst[t] + i0;
        *(f32x4*)d       = *(f32x4*)&v[0];
        *(f32x4*)(d + 4) = *(f32x4*)&v[4];
    }
}

// ---------------------------------------------------------------------------
// Pure-bf16 MFMA GEMM with 2-deep counted-vmcnt pipeline; LDS slot-XOR
// swizzle; 128x128 tile, BK=32, 4 waves. XCD-bijective swizzle.
// (round-4/7 proven config — frozen)
// ---------------------------------------------------------------------------
__global__ __launch_bounds__(256) void gemm_bf16(
    const unsigned short* __restrict__ A, const unsigned short* __restrict__ W,
    void* __restrict__ C, int Nout, int K,
    const float* __restrict__ bias,
    const void* resid, const int* rflag, long resid_row0,
    int act, int out_bf16)
{
    __shared__ unsigned short As[2][128 * 32];
    __shared__ unsigned short Bs[2][128 * 32];
    const int tid  = threadIdx.x;
    const int lane = tid & 63, wv = tid >> 6;
    const int wrow = wv >> 1, wcol = wv & 1;
    const int fm = lane & 15, quad = lane >> 4;

    const int gx = gridDim.x;
    const int nwg = gx * gridDim.y;
    int lin = blockIdx.y * gx + blockIdx.x;
    lin = (lin & 7) * (nwg >> 3) + (lin >> 3);
    const int bm = (lin / gx) * 128, bn = (lin % gx) * 128;

    const int sr   = tid >> 2;
    const int sb   = (((tid & 3) ^ ((sr >> 1) & 3)) * 16);
    const char* Ab = (const char*)A;
    const char* Wb = (const char*)W;
    const long a0 = ((long)(bm + sr) * K) * 2 + sb;
    const long a1 = ((long)(bm + 64 + sr) * K) * 2 + sb;
    const long b0 = ((long)(bn + sr) * K) * 2 + sb;
    const long b1 = ((long)(bn + 64 + sr) * K) * 2 + sb;
    const int ld = tid * 16;

    auto stage = [&](int bsel, int k0b) {
        char* AD = (char*)As[bsel];
        char* BD = (char*)Bs[bsel];
        gld16(Ab + a0 + k0b, AD + ld);
        gld16(Ab + a1 + k0b, AD + 4096 + ld);
        gld16(Wb + b0 + k0b, BD + ld);
        gld16(Wb + b1 + k0b, BD + 4096 + ld);
    };

    f32x4 acc[4][4] = {};
    const int nt = (K * 2) / 64;

    const int xsw = (fm >> 1) & 3;

    stage(0, 0);
    stage(1, 64);
    int cur = 0;
    for (int t = 0; t < nt; ++t) {
        if (t + 1 < nt) { asm volatile("s_waitcnt vmcnt(4)" ::: "memory"); }
        else            { asm volatile("s_waitcnt vmcnt(0)" ::: "memory"); }
        __builtin_amdgcn_sched_barrier(0);
        __builtin_amdgcn_s_barrier();
        __builtin_amdgcn_sched_barrier(0);

        const unsigned short* Ac = As[cur];
        const unsigned short* Bc = Bs[cur];
        bf16x8 af[4], bw[4];
        #pragma unroll
        for (int u = 0; u < 4; ++u) {
            const int qs = (quad ^ xsw) * 8;
            af[u] = *(const bf16x8*)&Ac[(wrow * 64 + u * 16 + fm) * 32 + qs];
            bw[u] = *(const bf16x8*)&Bc[(wcol * 64 + u * 16 + fm) * 32 + qs];
        }
        __builtin_amdgcn_s_setprio(1);
        #pragma unroll
        for (int i = 0; i < 4; ++i)
            #pragma unroll
            for (int j = 0; j < 4; ++j)
                acc[i][j] = __builtin_amdgcn_mfma_f32_16x16x32_bf16(
                                af[i], bw[j], acc[i][j], 0, 0, 0);
        __builtin_amdgcn_s_setprio(0);

        asm volatile("s_waitcnt lgkmcnt(0)" ::: "memory");
        __builtin_amdgcn_sched_barrier(0);
        __builtin_amdgcn_s_barrier();
        __builtin_amdgcn_sched_barrier(0);
        if (t + 2 < nt) stage(cur, (t + 2) * 64);
        cur ^= 1;
    }

    const int crow0 = bm + wrow * 64, ccol0 = bn + wcol * 64;
    if (out_bf16) {
        unsigned short* Cb = (unsigned short*)C;
        #pragma unroll
        for (int j = 0; j < 4; ++j) {
            const int col = ccol0 + j * 16 + fm;
            const float bv = bias ? bias[col] : 0.0f;
            #pragma unroll
            for (int i = 0; i < 4; ++i)
                #pragma unroll
                for (int r = 0; r < 4; ++r) {
                    const int row = crow0 + i * 16 + quad * 4 + r;
                    float v = acc[i][j][r] + bv;
                    if (act) v = gelu_exact(v);
                    Cb[(long)row * Nout + col] = f2bf(v);
                }
        }
    } else {
        float* Cf = (float*)C;
        const int rfl = resid ? (rflag ? *rflag : 1) : 1;
        #pragma unroll
        for (int j = 0; j < 4; ++j) {
            const int col = ccol0 + j * 16 + fm;
            const float bv = bias ? bias[col] : 0.0f;
            #pragma unroll
            for (int i = 0; i < 4; ++i)
                #pragma unroll
                for (int r = 0; r < 4; ++r) {
                    const int row = crow0 + i * 16 + quad * 4 + r;
                    float v = acc[i][j][r] + bv;
                    if (act)   v = gelu_exact(v);
                    if (resid) v += ldflex(resid, rfl, (resid_row0 + row) * (long)Nout + col);
                    Cf[(long)row * Nout + col] = v;
                }
        }
    }
}

// ---------------------------------------------------------------------------
// LayerNorm over rows of 512. Flex-dtype x/g/b; bf16 out. Vectorized loads:
// fp32 path = float2 (8B/lane coalesced), bf16 path = packed uint.
// ---------------------------------------------------------------------------
__global__ __launch_bounds__(256) void layernorm_512(
    const void* __restrict__ x, const int* __restrict__ xflag, long row0,
    const void* __restrict__ g, const int* __restrict__ gflag,
    const void* __restrict__ b, const int* __restrict__ bflag,
    unsigned short* __restrict__ o)
{
    const int row = blockIdx.x;
    const int tid = threadIdx.x;
    const int xf = xflag ? *xflag : 1;
    float vx, vy;
    if (xf) {
        const float2 t = ((const float2*)x)[(row0 + row) * 256 + tid];
        vx = t.x; vy = t.y;
    } else {
        const unsigned u = ((const unsigned*)x)[(row0 + row) * 256 + tid];
        vx = bf2f((unsigned short)u); vy = bf2f((unsigned short)(u >> 16));
    }
    float s  = vx + vy;
    float s2 = vx * vx + vy * vy;
    #pragma unroll
    for (int off = 32; off > 0; off >>= 1) {
        s  += __shfl_down(s, off);
        s2 += __shfl_down(s2, off);
    }
    __shared__ float ss[4], ss2[4];
    if ((tid & 63) == 0) { ss[tid >> 6] = s; ss2[tid >> 6] = s2; }
    __syncthreads();
    const float ts   = ss[0] + ss[1] + ss[2] + ss[3];
    const float ts2  = ss2[0] + ss2[1] + ss2[2] + ss2[3];
    const float mean = ts * (1.0f / 512.0f);
    const float var  = ts2 * (1.0f / 512.0f) - mean * mean;
    const float rstd = rsqrtf(var + 1e-5f);
    const int gf = *gflag, bff = *bflag;
    float gx_, gy_, bx_, by_;
    if (gf) { const float2 t = ((const float2*)g)[tid]; gx_ = t.x; gy_ = t.y; }
    else    { const unsigned u = ((const unsigned*)g)[tid];
              gx_ = bf2f((unsigned short)u); gy_ = bf2f((unsigned short)(u >> 16)); }
    if (bff) { const float2 t = ((const float2*)b)[tid]; bx_ = t.x; by_ = t.y; }
    else     { const unsigned u = ((const unsigned*)b)[tid];
               bx_ = bf2f((unsigned short)u); by_ = bf2f((unsigned short)(u >> 16)); }
    us2 r;
    r[0] = f2bf((vx - mean) * rstd * gx_ + bx_);
    r[1] = f2bf((vy - mean) * rstd * gy_ + by_);
    *(us2*)(o + (long)row * 512 + tid * 2) = r;
}

// ---------------------------------------------------------------------------
// MFMA flash attention, bf16 qkv in [b,n,3,H,64], bf16 o out [b,n,H,64].
// K/V register-prefetched ONE TILE AHEAD; barrier2 = raw s_barrier + lgkmcnt
// only (prefetch stays in flight). Row-sum via ones-column MFMA. Bias via
// padded per-head table. P/O packing via v_cvt_pk_bf16_f32.
// (round-7 proven 219 us version — defer-max REVERTED: its conditional
// alpha/mr4 array liveness spilled to scratch, +520 MB HBM writes, r10)
// ---------------------------------------------------------------------------
__global__ __launch_bounds__(256, 5) void attn_mfma(
    const unsigned short* __restrict__ qkv,
    const void* __restrict__ table, const int* __restrict__ tflag,
    unsigned short* __restrict__ o)
{
    __shared__ unsigned short Ks[512 * 8];     // fragment-linear K, 8 KB
    __shared__ unsigned short Vt[64 * 72];     // [d][key]   9.2 KB
    __shared__ unsigned short Pl[4][16 * 72];  // per-wave P [q][key] 9.2 KB
    __shared__ float Tbh[228];                 // padded per-head bias column

    const int tid  = threadIdx.x;
    const int lane = tid & 63, wv = tid >> 6;
    const int fm = lane & 15, quad = lane >> 4;

    // XCD-bijective swizzle: total = 128*nb, always divisible by 8.
    const int hw    = blockIdx.x + gridDim.x * (blockIdx.y + gridDim.y * blockIdx.z);
    const int total = gridDim.x * gridDim.y * gridDim.z;
    const int lin   = (hw & 7) * (total >> 3) + (hw >> 3);
    const int q0 = (lin & 15) * 64;
    const int h  = (lin >> 4) & 7;
    const int b  = lin >> 7;

    {   // cache this head's bias column, padded [225..227] = [224]
        const int tf = *tflag;
        if (tid < 228) {
            const int src = tid > 224 ? 224 : tid;
            Tbh[tid] = ldflex(table, tf, src * 8 + h);
        }
    }

    // Q fragments: A[m=fm -> q][k=quad*8+j -> d], 2 chains (d 0..31, 32..63)
    bf16x8 qa[2];
    {
        const unsigned short* qb = &qkv[(long)((b * 1024 + q0 + wv * 16 + fm) * 3) * 512
                                        + h * 64 + quad * 8];
        qa[0] = *(const bf16x8*)qb;
        qa[1] = *(const bf16x8*)(qb + 32);
    }

    // rel-pos bias running indices: idx_raw[c] decremented 126/tile; >=0 always
    const int qi0   = q0 + wv * 16 + quad * 4;
    const int base0 = 63 * (qi0 >> 5) + (qi0 & 31) + 1984;
    int idxr[4];
    #pragma unroll
    for (int c = 0; c < 4; ++c) {
        const int kj = c * 16 + fm;
        idxr[c] = base0 - (63 * (kj >> 5) + (kj & 31));
    }

    // ones B-frag for row-sum MFMA
    bf16x8 ones8;
    #pragma unroll
    for (int i = 0; i < 8; ++i) ones8[i] = (short)0x3F80;

    // K staging chunk decode (fragment-linear; 2 b128 writes per thread)
    const int kc_fm   = tid & 15;
    const int kc_quad = (tid >> 4) & 3;
    const int kc_ch   = (tid >> 6) & 1;
    const int kc_c0   = (tid >> 7) & 1;
    const char* qkvB  = (const char*)qkv;
    long ksrc = (((long)(b * 1024 + kc_c0 * 16 + kc_fm) * 3 + 1) * 512
                 + h * 64 + kc_ch * 32 + kc_quad * 8) * 2;

    // V staging: key = lane (conflict-free transpose writes), d-chunk = wave
    const int key_v = tid & 63;
    const int dv    = (tid >> 6) * 16;
    long vsrc = (((long)(b * 1024 + key_v) * 3 + 2) * 512 + h * 64 + dv) * 2;

    char* KsB = (char*)Ks;

    f32x4 acc[4] = {};          // O accumulator: col-tile c -> d, rows quad*4+r
    f32x4 accS = {};            // row-sum accumulator (online l)
    float mrow[4] = {-1e30f, -1e30f, -1e30f, -1e30f};

    // prologue: prefetch tile 0 K/V into registers
    us8 kv0 = *(const us8*)(qkvB + ksrc);
    us8 kv1 = *(const us8*)(qkvB + ksrc + 98304);
    us8 vv0 = *(const us8*)(qkvB + vsrc);
    us8 vv1 = *(const us8*)(qkvB + vsrc + 16);

    for (int kt = 0; kt < 16; ++kt) {
        __syncthreads();   // prior tile's LDS reads done (and Tbh/qa on iter 0)

        // write prefetched K/V regs to LDS
        *(us8*)(KsB + tid * 16)        = kv0;
        *(us8*)(KsB + 4096 + tid * 16) = kv1;
        #pragma unroll
        for (int i = 0; i < 8; ++i) Vt[(dv + i) * 72 + key_v]     = vv0[i];
        #pragma unroll
        for (int i = 0; i < 8; ++i) Vt[(dv + 8 + i) * 72 + key_v] = vv1[i];

        // issue NEXT tile's loads (stay in flight through this tile's compute)
        if (kt < 15) {
            ksrc += 196608; vsrc += 196608;
            kv0 = *(const us8*)(qkvB + ksrc);
            kv1 = *(const us8*)(qkvB + ksrc + 98304);
            vv0 = *(const us8*)(qkvB + vsrc);
            vv1 = *(const us8*)(qkvB + vsrc + 16);
        }

        // barrier2: LDS writes visible; does NOT drain vmcnt (prefetch lives)
        asm volatile("s_waitcnt lgkmcnt(0)" ::: "memory");
        __builtin_amdgcn_s_barrier();

        // S = Q K^T  (4 col-tiles x 2 k-chains), Ks reads = base + lane*16
        f32x4 sv[4];
        __builtin_amdgcn_s_setprio(1);
        #pragma unroll
        for (int c = 0; c < 4; ++c) {
            f32x4 z = {};
            z = __builtin_amdgcn_mfma_f32_16x16x32_bf16(
                    qa[0], *(const bf16x8*)&Ks[(((c * 2 + 0) * 4 + quad) * 16 + fm) * 8],
                    z, 0, 0, 0);
            z = __builtin_amdgcn_mfma_f32_16x16x32_bf16(
                    qa[1], *(const bf16x8*)&Ks[(((c * 2 + 1) * 4 + quad) * 16 + fm) * 8],
                    z, 0, 0, 0);
            sv[c] = z;
        }
        __builtin_amdgcn_s_setprio(0);

        // scale + rel-pos bias: idx_r = idx_0 + r into padded table
        #pragma unroll
        for (int c = 0; c < 4; ++c) {
            const int i0 = idxr[c] > 224 ? 224 : idxr[c];
            const float* tb = &Tbh[i0];
            idxr[c] -= 126;
            #pragma unroll
            for (int r = 0; r < 4; ++r)
                sv[c][r] = fmaf(sv[c][r], 0.125f, tb[r]);
        }

        // online softmax: max-reduce only (sum comes from ones-MFMA)
        float alpha[4];
        #pragma unroll
        for (int r = 0; r < 4; ++r) {
            float mr = fmaxf(fmaxf(sv[0][r], sv[1][r]), fmaxf(sv[2][r], sv[3][r]));
            #pragma unroll
            for (int off = 1; off < 16; off <<= 1) mr = fmaxf(mr, __shfl_xor(mr, off));
            const float mnew = fmaxf(mrow[r], mr);
            alpha[r] = __expf(mrow[r] - mnew);
            mrow[r] = mnew;
            #pragma unroll
            for (int c = 0; c < 4; ++c)
                sv[c][r] = __expf(sv[c][r] - mnew);
        }

        // P: C layout -> LDS [q][key] via paired cvt_pk (per-wave region)
        unsigned short* Pw = Pl[wv];
        #pragma unroll
        for (int r = 0; r < 4; ++r) {
            const unsigned u01 = cvtpk_bf16(sv[0][r], sv[1][r]);
            const unsigned u23 = cvtpk_bf16(sv[2][r], sv[3][r]);
            const int row = (quad * 4 + r) * 72;
            Pw[row + fm]      = (unsigned short)u01;
            Pw[row + 16 + fm] = (unsigned short)(u01 >> 16);
            Pw[row + 32 + fm] = (unsigned short)u23;
            Pw[row + 48 + fm] = (unsigned short)(u23 >> 16);
        }

        // PV: A frag = P[q=fm][key=chain*32+quad*8+j]; B frag = Vt[d][key]
        const bf16x8 ap0 = *(const bf16x8*)&Pw[fm * 72 + quad * 8];
        const bf16x8 ap1 = *(const bf16x8*)&Pw[fm * 72 + 32 + quad * 8];
        __builtin_amdgcn_s_setprio(1);
        #pragma unroll
        for (int c = 0; c < 4; ++c) {
            #pragma unroll
            for (int r = 0; r < 4; ++r) acc[c][r] *= alpha[r];
            acc[c] = __builtin_amdgcn_mfma_f32_16x16x32_bf16(
                        ap0, *(const bf16x8*)&Vt[(c * 16 + fm) * 72 + quad * 8], acc[c], 0, 0, 0);
            acc[c] = __builtin_amdgcn_mfma_f32_16x16x32_bf16(
                        ap1, *(const bf16x8*)&Vt[(c * 16 + fm) * 72 + 32 + quad * 8], acc[c], 0, 0, 0);
        }
        #pragma unroll
        for (int r = 0; r < 4; ++r) accS[r] *= alpha[r];
        accS = __builtin_amdgcn_mfma_f32_16x16x32_bf16(ap0, ones8, accS, 0, 0, 0);
        accS = __builtin_amdgcn_mfma_f32_16x16x32_bf16(ap1, ones8, accS, 0, 0, 0);
        __builtin_amdgcn_s_setprio(0);
    }

    float rinv[4];
    #pragma unroll
    for (int r = 0; r < 4; ++r) rinv[r] = 1.0f / accS[r];
    #pragma unroll
    for (int r = 0; r < 4; ++r) {
        const long ob = (long)(b * 1024 + q0 + wv * 16 + quad * 4 + r) * 512 + h * 64;
        const unsigned u01 = cvtpk_bf16(acc[0][r] * rinv[r], acc[1][r] * rinv[r]);
        const unsigned u23 = cvtpk_bf16(acc[2][r] * rinv[r], acc[3][r] * rinv[r]);
        o[ob + fm]      = (unsigned short)u01;
        o[ob + 16 + fm] = (unsigned short)(u01 >> 16);
        o[ob + 32 + fm] = (unsigned short)u23;
        o[ob + 48 + fm] = (unsigned short)(u23 >> 16);
    }
}

extern "C" void kernel_launch(void* const* d_in, const int* in_sizes, int n_in,
                              void* d_out, int out_size, void* d_ws, size_t ws_size,
                              hipStream_t stream)
{
    (void)n_in; (void)out_size;
    float* out = (float*)d_out;

    constexpr int B = 32, N = 1024;

    int* flags = (int*)d_ws;
    {
        SniffArgs sa;
        for (int t = 0; t < 13; ++t) { sa.p[t] = d_in[t]; sa.n[t] = in_sizes[t]; }
        sniff_all<<<13, 64, 0, stream>>>(sa, flags);
    }

    // workspace layout: flags(256) | bf16 weights | fp32 biases | bf16 scratch
    unsigned short* Wq = (unsigned short*)((char*)d_ws + 256);  // [1536,512]
    unsigned short* Wp = Wq + 786432;                           // [512,512]
    unsigned short* W1 = Wp + 262144;                           // [2048,512]
    unsigned short* W2 = W1 + 1048576;                          // [512,2048]
    float* Bp = (float*)(W2 + 1048576);                         // 512
    float* B1 = Bp + 512;                                       // 2048
    float* B2 = B1 + 2048;                                      // 512
    char* scr = (char*)(B2 + 512);
    scr = (char*)(((size_t)scr + 255) & ~(size_t)255);

    {
        CvtArgs ca;
        ca.src[0] = d_in[1]; ca.dst[0] = Wq; ca.fidx[0] = 1; ca.n[0] = 786432;  ca.tobf[0] = 1;
        ca.src[1] = d_in[2]; ca.dst[1] = Wp; ca.fidx[1] = 2; ca.n[1] = 262144;  ca.tobf[1] = 1;
        ca.src[2] = d_in[4]; ca.dst[2] = W1; ca.fidx[2] = 4; ca.n[2] = 1048576; ca.tobf[2] = 1;
        ca.src[3] = d_in[6]; ca.dst[3] = W2; ca.fidx[3] = 6; ca.n[3] = 1048576; ca.tobf[3] = 1;
        ca.src[4] = d_in[3]; ca.dst[4] = Bp; ca.fidx[4] = 3; ca.n[4] = 512;     ca.tobf[4] = 0;
        ca.src[5] = d_in[5]; ca.dst[5] = B1; ca.fidx[5] = 5; ca.n[5] = 2048;    ca.tobf[5] = 0;
        ca.src[6] = d_in[7]; ca.dst[6] = B2; ca.fidx[6] = 7; ca.n[6] = 512;     ca.tobf[6] = 0;
        convert_params<<<dim3(512, 7), 256, 0, stream>>>(ca, flags);
    }

    const size_t fixed = (size_t)(scr - (char*)d_ws);
    const size_t per_batch = (size_t)N * 3072 * 2;   // Ln(512)+Hd(2048)+Ao(512) bf16
    int bpc = (int)((ws_size - fixed) / per_batch);
    if (bpc < 1) bpc = 1;
    if (bpc > B) bpc = B;

    unsigned short* Ln = (unsigned short*)scr;
    unsigned short* Hd = Ln + (size_t)bpc * N * 512;
    unsigned short* Ao = Hd + (size_t)bpc * N * 2048;

    // Phase 1: LN1 -> qkv -> attention -> proj (+bias, +x residual)
    for (int b0 = 0; b0 < B; b0 += bpc) {
        const int nb   = (B - b0) < bpc ? (B - b0) : bpc;
        const int rows = nb * N;
        const long r0  = (long)b0 * N;

        layernorm_512<<<rows, 256, 0, stream>>>(
            d_in[0], flags + 0, r0, d_in[8], flags + 8, d_in[9], flags + 9, Ln);
        gemm_bf16<<<dim3(12, rows / 128), 256, 0, stream>>>(
            Ln, Wq, Hd, 1536, 512, nullptr, nullptr, nullptr, 0, 0, 1);
        attn_mfma<<<dim3(16, 8, nb), 256, 0, stream>>>(
            Hd, d_in[12], flags + 12, Ao);
        gemm_bf16<<<dim3(4, rows / 128), 256, 0, stream>>>(
            Ao, Wp, out + r0 * 512, 512, 512,
            Bp, d_in[0], flags + 0, r0, 0, 0);
    }

    // Phase 2: LN2 -> mlp1 (+bias, gelu) -> mlp2 (+bias, +residual in-place)
    for (int b0 = 0; b0 < B; b0 += bpc) {
        const int nb   = (B - b0) < bpc ? (B - b0) : bpc;
        const int rows = nb * N;
        const long r0  = (long)b0 * N;

        layernorm_512<<<rows, 256, 0, stream>>>(
            out + r0 * 512, nullptr, 0, d_in[10], flags + 10, d_in[11], flags + 11, Ln);
        gemm_bf16<<<dim3(16, rows / 128), 256, 0, stream>>>(
            Ln, W1, Hd, 2048, 512, B1, nullptr, nullptr, 0, 1, 1);
        gemm_bf16<<<dim3(4, rows / 128), 256, 0, stream>>>(
            Hd, W2, out + r0 * 512, 512, 2048,
            B2, out + r0 * 512, nullptr, 0, 0, 0);
    }
}